// Round 4
// baseline (10590.988 us; speedup 1.0000x reference)
//
#include <hip/hip_runtime.h>

#define NF 8
#define RD 256
#define RMASK 255

typedef float f2 __attribute__((ext_vector_type(2)));
typedef float f4 __attribute__((ext_vector_type(4)));

template <int CTRL>
__device__ __forceinline__ float qp(float x) {
  return __int_as_float(
      __builtin_amdgcn_update_dpp(0, __float_as_int(x), CTRL, 0xF, 0xF, true));
}

// Raw barrier: LDS-ordering only (global ops stay in flight across phases).
__device__ __forceinline__ void wg_barrier() {
  asm volatile("s_waitcnt lgkmcnt(0)" ::: "memory");
  __builtin_amdgcn_s_barrier();
  __builtin_amdgcn_sched_barrier(0);
}

#define WAIT_VM(N) asm volatile("s_waitcnt vmcnt(" #N ")" ::: "memory")

// Coherent (device-scope) loads/stores: sc0 sc1 -> data at coherence point,
// no wbl2/inv fences needed. Loads are INVALID until a WAIT_VM.
__device__ __forceinline__ float ld_cohf(const float* p) {
  float v;
  asm volatile("global_load_dword %0, %1, off sc0 sc1" : "=v"(v) : "v"(p) : "memory");
  return v;
}
__device__ __forceinline__ int ld_cohi(const int* p) {
  int v;
  asm volatile("global_load_dword %0, %1, off sc0 sc1" : "=v"(v) : "v"(p) : "memory");
  return v;
}
__device__ __forceinline__ void st_cohf(float* p, float v) {
  asm volatile("global_store_dword %0, %1, off sc0 sc1" :: "v"(p), "v"(v) : "memory");
}
__device__ __forceinline__ void st_cohi(int* p, int v) {
  asm volatile("global_store_dword %0, %1, off sc0 sc1" :: "v"(p), "v"(v) : "memory");
}

// R11: 3 blocks. b0 = L0 (4 cell waves + pub/tbuf). b1 = L1 (4 cell waves +
// dma: fills h0loc from ring0, publishes h1 -> ring1). b2 = head (1 wave,
// self-paced: hid/out verbatim R7 math, direct outp stores; no barriers).
// Flags/rings use hand-rolled sc0sc1 write-through + counted vmcnt (never a
// full drain in the steady loop). flag values lag by 6 so counted waits are
// free. Cell arithmetic verbatim R7/R10 -> bit-identical recurrence.
__global__ __launch_bounds__(320, 1) void decoder_p11(
    const float* __restrict__ h0in, const float* __restrict__ c0in,
    const float* __restrict__ diffp, const float* __restrict__ target,
    const float* __restrict__ Wih0, const float* __restrict__ Whh0,
    const float* __restrict__ bih0, const float* __restrict__ bhh0,
    const float* __restrict__ Wih1, const float* __restrict__ Whh1,
    const float* __restrict__ bih1, const float* __restrict__ bhh1,
    const float* __restrict__ Whid, const float* __restrict__ bhidp,
    const float* __restrict__ Woutp, const float* __restrict__ boutp,
    float* __restrict__ outp, float* __restrict__ ws, const int T)
{
  const int tid = threadIdx.x;
  const int wv  = tid >> 6;
  const int l   = tid & 63;
  const int q   = l >> 2;
  const int k   = l & 3;
  const int u   = 16 * (wv & 3) + q;
  const int r   = 64 * k + u;
  const bool isk0 = (k == 0);
  const float am = (k == 2) ? 2.0f : 1.0f;
  const float ab = (k == 2) ? -1.0f : 0.0f;

  __shared__ alignas(256) float h0r[4][64];        // b0
  __shared__ alignas(256) float tbuf[2][32 * NF];  // b0
  __shared__ alignas(256) float h0loc[16][64];     // b1
  __shared__ alignas(256) float h1r[4][64];        // b1
  __shared__ alignas(256) float h1loc[8][64];      // b2
  __shared__ alignas(256) float hidS[4][32];       // b2
  __shared__ float ldspad[20480];                  // 80KB: 1 block/CU

  if (T < 0) {  // never true; keeps ldspad allocated
    ldspad[tid] = h0in[tid];
    __syncthreads();
    outp[0] = ldspad[319 - tid];
  }

  int* flag0p = (int*)ws;          // h0 steps durable in ring0
  int* cons0p = (int*)ws + 16;     // b1 dma fill progress
  int* flag1p = (int*)ws + 32;     // h1 steps durable in ring1
  int* cons1p = (int*)ws + 48;     // b2 progress
  float* ring0 = ws + 256;
  float* ring1 = ws + 256 + RD * 64;

  if (blockIdx.x == 0) {
    // ================= BLOCK 0 : layer 0 =================
    f2 wreg[36];
    float b_ = 0.f, xd = 0.f, cS = 0.f, hS = 0.f, xc = 0.f;
    if (wv < 4) {
      #pragma unroll
      for (int j = 0; j < 4; ++j) {
        const int row = 64 * ((k + j) & 3) + u;
        const float* rp = Whh0 + row * 64 + 16 * k;
        #pragma unroll
        for (int c = 0; c < 4; ++c) {
          f4 v = *(const f4*)(rp + 4 * ((c + k) & 3));
          wreg[8 * j + 2 * c]     = v.lo;
          wreg[8 * j + 2 * c + 1] = v.hi;
        }
      }
      b_ = bih0[r] + bhh0[r];
      const float* ra = Wih0 + r * 14;
      #pragma unroll
      for (int c = 0; c < 4; ++c) wreg[32 + c] = (f2){ra[2 * c], ra[2 * c + 1]};
      #pragma unroll
      for (int m = 0; m < 6; ++m) xd += ra[8 + m] * diffp[m];
      if (isk0) cS = c0in[u];
      if (wv == 0) h0r[3][l] = h0in[l];
    } else {
      if (l < T) {  // seed tbuf rows 0..63 (both buffers)
        *(f4*)&((float*)tbuf)[l * 8]     = *(const f4*)&target[l * 8];
        *(f4*)&((float*)tbuf)[l * 8 + 4] = *(const f4*)&target[l * 8 + 4];
      }
    }
    __syncthreads();

    int cons0L = 0;
    f4 tr0 = {0.f, 0.f, 0.f, 0.f}, tr1 = {0.f, 0.f, 0.f, 0.f};
    for (int t = 0; t <= T; ++t) {
      if (wv < 4) {
        if (t < T) {
          const float* base = &h0r[(t - 1) & 3][16 * k];
          f2 P0 = {0.f,0.f}, P1 = {0.f,0.f}, P2 = {0.f,0.f}, P3 = {0.f,0.f};
          #pragma unroll
          for (int c = 0; c < 4; ++c) {
            f4 v = *(const f4*)(base + 4 * ((c + k) & 3));
            P0 += wreg[2*c] * v.lo;      P0 += wreg[2*c+1] * v.hi;
            P1 += wreg[8+2*c] * v.lo;    P1 += wreg[8+2*c+1] * v.hi;
            P2 += wreg[16+2*c] * v.lo;   P2 += wreg[16+2*c+1] * v.hi;
            P3 += wreg[24+2*c] * v.lo;   P3 += wreg[24+2*c+1] * v.hi;
          }
          float p0 = P0.x + P0.y, p1 = P1.x + P1.y;
          float p2 = P2.x + P2.y, p3 = P3.x + P3.y;
          float g = ((p0 + qp<0x39>(p3)) + (qp<0x4E>(p2) + qp<0x93>(p1))) + b_ + xc;
          float e = __expf(-g * am);
          float s = __fdividef(1.0f, 1.0f + e);
          float a = fmaf(s, am, ab);
          float A1 = qp<0xB1>(a), A2 = qp<0x4E>(a), A3 = qp<0x1B>(a);
          if (isk0) {
            cS = A1 * cS + a * A2;
            float e2 = __expf(-2.0f * cS);
            hS = A3 * (__fdividef(2.0f, 1.0f + e2) - 1.0f);
            h0r[t & 3][u] = hS;
          }
        }
        if (t < T - 1) {
          const f4* trow = (const f4*)&tbuf[(t >> 5) & 1][(t & 31) * NF];
          f4 r0 = trow[0], r1 = trow[1];
          f2 s2 = wreg[32] * r0.lo; s2 += wreg[33] * r0.hi;
          s2 += wreg[34] * r1.lo;   s2 += wreg[35] * r1.hi;
          xc = xd + s2.x + s2.y;
        } else xc = 0.f;
      } else {
        // -------- pub0: release, backpressure, ring store, tbuf --------
        if ((t & 3) == 0 && t >= 8) {
          WAIT_VM(4);   // FIFO: ring entries <= t-7 durable; 4 newest in flight
          if (l == 0) st_cohi(flag0p, t - 6);
        }
        if ((t & 63) == 0 && t > RD - 64) {
          while (t - cons0L > RD - 64) {
            cons0L = ld_cohi(cons0p);
            WAIT_VM(0);
          }
        }
        if (t >= 1) {
          float hv = h0r[(t - 1) & 3][l];
          st_cohf(&ring0[((t - 1) & RMASK) * 64 + l], hv);
        }
        const int ph = t & 31;
        const int cl = (t >> 5) + 1;
        if (l < 32 && cl * 32 < T) {
          if (ph == 8) {
            tr0 = *(const f4*)&target[cl * 256 + l * 8];
            tr1 = *(const f4*)&target[cl * 256 + l * 8 + 4];
          } else if (ph == 26) {
            *(f4*)&tbuf[cl & 1][l * 8]     = tr0;
            *(f4*)&tbuf[cl & 1][l * 8 + 4] = tr1;
          }
        }
      }
      wg_barrier();
    }
    if (wv == 4) {
      WAIT_VM(0);
      if (l == 0) st_cohi(flag0p, T);
    }
    if (wv < 4 && isk0) {
      outp[T * NF + u]       = hS;   // h_final layer 0
      outp[T * NF + 128 + u] = cS;   // c_final layer 0
    }
  } else if (blockIdx.x == 1) {
    // ================= BLOCK 1 : layer 1 =================
    f2 wreg[64];
    float b_ = 0.f, cS = 0.f, hS = 0.f;
    if (wv < 4) {
      const float* Wsrc = (k < 2) ? Wih1 : Whh1;
      const int co = 32 * (k & 1);
      #pragma unroll
      for (int j = 0; j < 4; ++j) {
        const int row = 64 * ((k + j) & 3) + u;
        const float* rp = Wsrc + row * 64 + co;
        #pragma unroll
        for (int c = 0; c < 8; ++c) {
          f4 v = *(const f4*)(rp + 4 * ((c + 2 * k) & 7));
          wreg[16 * j + 2 * c]     = v.lo;
          wreg[16 * j + 2 * c + 1] = v.hi;
        }
      }
      b_ = bih1[r] + bhh1[r];
      if (isk0) cS = c0in[64 + u];
      if (wv == 0) h1r[3][l] = h0in[64 + l];
    }
    // dma state
    int flagL = 0, fillW = 0, nPend = 0, F_pend = 0, cons1L = 0;
    float pb0 = 0.f, pb1 = 0.f, pb2 = 0.f, pb3 = 0.f;
    if (wv == 4) {
      const int pre = (T < 4) ? T : 4;
      while (flagL < pre) {
        flagL = ld_cohi(flag0p);
        WAIT_VM(0);
      }
      for (int s = 0; s < pre; ++s) {
        float v = ld_cohf(&ring0[(s & RMASK) * 64 + l]);
        WAIT_VM(0);
        h0loc[s & 15][l] = v;
      }
      fillW = pre;
      F_pend = flagL;
    }
    __syncthreads();

    for (int p = 0; p <= T; ++p) {
      if (wv < 4) {
        if (p < T) {
          const float* base = (k < 2) ? &h0loc[p & 15][32 * (k & 1)]
                                      : &h1r[(p - 1) & 3][32 * (k & 1)];
          f2 P0 = {0.f,0.f}, P1 = {0.f,0.f}, P2 = {0.f,0.f}, P3 = {0.f,0.f};
          #pragma unroll
          for (int c = 0; c < 8; ++c) {
            f4 v = *(const f4*)(base + 4 * ((c + 2 * k) & 7));
            P0 += wreg[2*c] * v.lo;      P0 += wreg[2*c+1] * v.hi;
            P1 += wreg[16+2*c] * v.lo;   P1 += wreg[16+2*c+1] * v.hi;
            P2 += wreg[32+2*c] * v.lo;   P2 += wreg[32+2*c+1] * v.hi;
            P3 += wreg[48+2*c] * v.lo;   P3 += wreg[48+2*c+1] * v.hi;
          }
          float p0 = P0.x + P0.y, p1 = P1.x + P1.y;
          float p2 = P2.x + P2.y, p3 = P3.x + P3.y;
          float g = ((p0 + qp<0x39>(p3)) + (qp<0x4E>(p2) + qp<0x93>(p1))) + b_;
          float e = __expf(-g * am);
          float s = __fdividef(1.0f, 1.0f + e);
          float a = fmaf(s, am, ab);
          float A1 = qp<0xB1>(a), A2 = qp<0x4E>(a), A3 = qp<0x1B>(a);
          if (isk0) {
            cS = A1 * cS + a * A2;
            float e2 = __expf(-2.0f * cS);
            hS = A3 * (__fdividef(2.0f, 1.0f + e2) - 1.0f);
            h1r[p & 3][u] = hS;
          }
        }
      } else if (wv == 4) {
        // -------- dma: consume pending, plan loads, publish h1 --------
        WAIT_VM(1);   // pending loads (issued p-1) done; newest h1 store may fly
        if (nPend > 0) h0loc[(fillW + 0) & 15][l] = pb0;
        if (nPend > 1) h0loc[(fillW + 1) & 15][l] = pb1;
        if (nPend > 2) h0loc[(fillW + 2) & 15][l] = pb2;
        if (nPend > 3) h0loc[(fillW + 3) & 15][l] = pb3;
        fillW += nPend;
        nPend = 0;
        if ((p & 3) == 1) flagL = F_pend;   // adopt poll issued at p-1
        {  // emergency (startup/starved only)
          int need = p + 2; if (need > T) need = T;
          while (fillW < need) {
            while (flagL < fillW + 1) {
              flagL = ld_cohi(flag0p);
              WAIT_VM(0);
            }
            float v = ld_cohf(&ring0[(fillW & RMASK) * 64 + l]);
            WAIT_VM(0);
            h0loc[fillW & 15][l] = v;
            ++fillW;
          }
        }
        if ((p & 3) == 0 && p >= 8 && l == 0)
          st_cohi(flag1p, p - 6);   // outstanding <=1 (from p-1) => safe
        if ((p & 63) == 0 && p > RD - 64) {
          while (p - cons1L > RD - 64) {
            cons1L = ld_cohi(cons1p);
            WAIT_VM(0);
          }
        }
        if ((p & 3) == 0) F_pend = ld_cohi(flag0p);   // adopt at p+1
        {
          int want = flagL;
          if (want > p + 10) want = p + 10;
          if (want > T) want = T;
          int n = want - fillW;
          if (n < 0) n = 0;
          if (n > 4) n = 4;
          if (n > 0) pb0 = ld_cohf(&ring0[((fillW + 0) & RMASK) * 64 + l]);
          if (n > 1) pb1 = ld_cohf(&ring0[((fillW + 1) & RMASK) * 64 + l]);
          if (n > 2) pb2 = ld_cohf(&ring0[((fillW + 2) & RMASK) * 64 + l]);
          if (n > 3) pb3 = ld_cohf(&ring0[((fillW + 3) & RMASK) * 64 + l]);
          nPend = n;
        }
        if (p >= 1) {
          float hv = h1r[(p - 1) & 3][l];
          st_cohf(&ring1[((p - 1) & RMASK) * 64 + l], hv);
        }
        if ((p & 63) == 32 && l == 0) st_cohi(cons0p, fillW);
      }
      wg_barrier();
    }
    if (wv == 4) {
      WAIT_VM(0);
      if (l == 0) st_cohi(flag1p, T);
    }
    if (wv < 4 && isk0) {
      outp[T * NF + 64 + u]  = hS;   // h_final layer 1
      outp[T * NF + 192 + u] = cS;   // c_final layer 1
    }
  } else {
    // ================= BLOCK 2 : head (self-paced, 1 wave) =================
    if (wv != 0) return;
    f2 wH[16], wO[4];
    float bhA = 0.f, bhB = 0.f, bo_ = 0.f;
    #pragma unroll
    for (int i = 0; i < 2; ++i) {
      const float* rp = Whid + (2 * q + i) * 64 + 16 * k;
      #pragma unroll
      for (int c = 0; c < 4; ++c) {
        f4 v = *(const f4*)(rp + 4 * ((c + k) & 3));
        wH[8 * i + 2 * c]     = v.lo;
        wH[8 * i + 2 * c + 1] = v.hi;
      }
    }
    bhA = bhidp[2 * q];
    bhB = bhidp[2 * q + 1];
    if (q < 8) {
      const float* rp = Woutp + q * 32 + 8 * k;
      #pragma unroll
      for (int c = 0; c < 2; ++c) {
        f4 v = *(const f4*)(rp + 4 * ((c + k) & 1));
        wO[2 * c]     = v.lo;
        wO[2 * c + 1] = v.hi;
      }
      bo_ = boutp[q];
    }
    int f1L = 0;
    for (int s0 = 0; s0 < T; s0 += 8) {
      const int B = (T - s0 < 8) ? (T - s0) : 8;
      while (f1L < s0 + B) {
        f1L = ld_cohi(flag1p);
        WAIT_VM(0);
      }
      float rb[8];
      #pragma unroll
      for (int i = 0; i < 8; ++i)
        if (i < B) rb[i] = ld_cohf(&ring1[((s0 + i) & RMASK) * 64 + l]);
      WAIT_VM(0);
      #pragma unroll
      for (int i = 0; i < 8; ++i)
        if (i < B) h1loc[(s0 + i) & 7][l] = rb[i];
      #pragma unroll
      for (int i = 0; i < 8; ++i) {
        if (i < B) {
          const int s = s0 + i;
          // hid (R7 wv0 verbatim)
          const float* hp = &h1loc[s & 7][16 * k];
          f2 pa = {0.f,0.f}, pb = {0.f,0.f};
          #pragma unroll
          for (int c = 0; c < 4; ++c) {
            f4 v = *(const f4*)(hp + 4 * ((c + k) & 3));
            pa += wH[2*c] * v.lo;     pa += wH[2*c+1] * v.hi;
            pb += wH[8+2*c] * v.lo;   pb += wH[8+2*c+1] * v.hi;
          }
          float sa = pa.x + pa.y; sa += qp<0xB1>(sa); sa += qp<0x4E>(sa);
          float sb = pb.x + pb.y; sb += qp<0xB1>(sb); sb += qp<0x4E>(sb);
          if (isk0) *(f2*)&hidS[s & 3][2 * q] = (f2){sa + bhA, sb + bhB};
          // out (R7 wv1 verbatim)
          if (q < 8) {
            const float* hq = &hidS[s & 3][8 * k];
            f2 po = {0.f,0.f};
            #pragma unroll
            for (int c = 0; c < 2; ++c) {
              f4 v = *(const f4*)(hq + 4 * ((c + k) & 1));
              po += wO[2*c] * v.lo; po += wO[2*c+1] * v.hi;
            }
            float so = po.x + po.y; so += qp<0xB1>(so); so += qp<0x4E>(so);
            if (isk0) outp[s * NF + q] = rintf(so + bo_);
          }
        }
      }
      if ((s0 & 63) == 0 && s0 > 0 && l == 0) st_cohi(cons1p, s0);
    }
  }
}

extern "C" void kernel_launch(void* const* d_in, const int* in_sizes, int n_in,
                              void* d_out, int out_size, void* d_ws, size_t ws_size,
                              hipStream_t stream) {
  const float* h0in   = (const float*)d_in[1];
  const float* c0in   = (const float*)d_in[2];
  const float* diffp  = (const float*)d_in[3];
  const float* target = (const float*)d_in[4];
  const float* Wih0   = (const float*)d_in[5];
  const float* Whh0   = (const float*)d_in[6];
  const float* bih0   = (const float*)d_in[7];
  const float* bhh0   = (const float*)d_in[8];
  const float* Wih1   = (const float*)d_in[9];
  const float* Whh1   = (const float*)d_in[10];
  const float* bih1   = (const float*)d_in[11];
  const float* bhh1   = (const float*)d_in[12];
  const float* Whid   = (const float*)d_in[13];
  const float* bhidp  = (const float*)d_in[14];
  const float* Woutp  = (const float*)d_in[15];
  const float* boutp  = (const float*)d_in[16];
  float* outp = (float*)d_out;
  const int T = in_sizes[4] / NF;

  hipMemsetAsync(d_ws, 0, 256, stream);   // zero flags (graph-capturable)
  decoder_p11<<<dim3(3), dim3(320), 0, stream>>>(
      h0in, c0in, diffp, target,
      Wih0, Whh0, bih0, bhh0,
      Wih1, Whh1, bih1, bhh1,
      Whid, bhidp, Woutp, boutp,
      outp, (float*)d_ws, T);
}

// Round 7
// 10511.195 us; speedup vs baseline: 1.0076x; 1.0076x over previous
//
#include <hip/hip_runtime.h>

#define NF 8
#define RD 256
#define RMASK 255

typedef float f2 __attribute__((ext_vector_type(2)));
typedef float f4 __attribute__((ext_vector_type(4)));

template <int CTRL>
__device__ __forceinline__ float qp(float x) {
  return __int_as_float(
      __builtin_amdgcn_update_dpp(0, __float_as_int(x), CTRL, 0xF, 0xF, true));
}

// Raw barrier: LDS-ordering only (global ops stay in flight across phases).
__device__ __forceinline__ void wg_barrier() {
  asm volatile("s_waitcnt lgkmcnt(0)" ::: "memory");
  __builtin_amdgcn_s_barrier();
  __builtin_amdgcn_sched_barrier(0);
}

#define WAIT_VM(N) asm volatile("s_waitcnt vmcnt(" #N ")" ::: "memory")

// Coherent (device-scope) loads/stores: sc0 sc1 -> data at coherence point.
// Loads are INVALID until a covering WAIT_VM.
__device__ __forceinline__ float ld_cohf(const float* p) {
  float v;
  asm volatile("global_load_dword %0, %1, off sc0 sc1" : "=v"(v) : "v"(p) : "memory");
  return v;
}
__device__ __forceinline__ int ld_cohi(const int* p) {
  int v;
  asm volatile("global_load_dword %0, %1, off sc0 sc1" : "=v"(v) : "v"(p) : "memory");
  return v;
}
__device__ __forceinline__ void st_cohf(float* p, float v) {
  asm volatile("global_store_dword %0, %1, off sc0 sc1" :: "v"(p), "v"(v) : "memory");
}
__device__ __forceinline__ void st_cohi(int* p, int v) {
  asm volatile("global_store_dword %0, %1, off sc0 sc1" :: "v"(p), "v"(v) : "memory");
}

// R14 = R11 byte-exact (verified PASS @10582us) + ONE change: s_setprio.
// Theory: each block runs 5 waves on 4 SIMDs -> one SIMD carries a cell wave
// AND the pub/dma wave at equal priority; that cell wave's issue rate halves
// and the per-phase barrier convoys the block to its pace (~half the
// unexplained 600cy/phase). Cells get prio 1, pub/dma stays prio 0 (T5
// mechanism: role-split waves -> scheduler can prefer the critical role).
// The 3-deep dma pipeline (R12/R13) is ABANDONED: flaky h_final corruption
// (0.108/0.045) that two op-count audits can't explain -> unverified HW
// assumption (store retirement vs cross-XCD visibility); R11's 1-deep flight
// is the last protocol with a clean pass.
__global__ __launch_bounds__(320, 1) void decoder_p14(
    const float* __restrict__ h0in, const float* __restrict__ c0in,
    const float* __restrict__ diffp, const float* __restrict__ target,
    const float* __restrict__ Wih0, const float* __restrict__ Whh0,
    const float* __restrict__ bih0, const float* __restrict__ bhh0,
    const float* __restrict__ Wih1, const float* __restrict__ Whh1,
    const float* __restrict__ bih1, const float* __restrict__ bhh1,
    const float* __restrict__ Whid, const float* __restrict__ bhidp,
    const float* __restrict__ Woutp, const float* __restrict__ boutp,
    float* __restrict__ outp, float* __restrict__ ws, const int T)
{
  const int tid = threadIdx.x;
  const int wv  = tid >> 6;
  const int l   = tid & 63;
  const int q   = l >> 2;
  const int k   = l & 3;
  const int u   = 16 * (wv & 3) + q;
  const int r   = 64 * k + u;
  const bool isk0 = (k == 0);
  const float am = (k == 2) ? 2.0f : 1.0f;
  const float ab = (k == 2) ? -1.0f : 0.0f;

  __shared__ alignas(256) float h0r[4][64];        // b0
  __shared__ alignas(256) float tbuf[2][32 * NF];  // b0
  __shared__ alignas(256) float h0loc[16][64];     // b1
  __shared__ alignas(256) float h1r[4][64];        // b1
  __shared__ alignas(256) float h1loc[8][64];      // b2
  __shared__ alignas(256) float hidS[4][32];       // b2
  __shared__ float ldspad[20480];                  // 80KB: 1 block/CU

  if (T < 0) {  // never true; keeps ldspad allocated
    ldspad[tid] = h0in[tid];
    __syncthreads();
    outp[0] = ldspad[319 - tid];
  }

  int* flag0p = (int*)ws;          // h0 steps durable in ring0
  int* cons0p = (int*)ws + 16;     // b1 dma fill progress
  int* flag1p = (int*)ws + 32;     // h1 steps durable in ring1
  int* cons1p = (int*)ws + 48;     // b2 progress
  float* ring0 = ws + 256;
  float* ring1 = ws + 256 + RD * 64;

  if (blockIdx.x == 0) {
    // ================= BLOCK 0 : layer 0 =================
    f2 wreg[36];
    float b_ = 0.f, xd = 0.f, cS = 0.f, hS = 0.f, xc = 0.f;
    if (wv < 4) {
      #pragma unroll
      for (int j = 0; j < 4; ++j) {
        const int row = 64 * ((k + j) & 3) + u;
        const float* rp = Whh0 + row * 64 + 16 * k;
        #pragma unroll
        for (int c = 0; c < 4; ++c) {
          f4 v = *(const f4*)(rp + 4 * ((c + k) & 3));
          wreg[8 * j + 2 * c]     = v.lo;
          wreg[8 * j + 2 * c + 1] = v.hi;
        }
      }
      b_ = bih0[r] + bhh0[r];
      const float* ra = Wih0 + r * 14;
      #pragma unroll
      for (int c = 0; c < 4; ++c) wreg[32 + c] = (f2){ra[2 * c], ra[2 * c + 1]};
      #pragma unroll
      for (int m = 0; m < 6; ++m) xd += ra[8 + m] * diffp[m];
      if (isk0) cS = c0in[u];
      if (wv == 0) h0r[3][l] = h0in[l];
    } else {
      if (l < T) {  // seed tbuf rows 0..63 (both buffers)
        *(f4*)&((float*)tbuf)[l * 8]     = *(const f4*)&target[l * 8];
        *(f4*)&((float*)tbuf)[l * 8 + 4] = *(const f4*)&target[l * 8 + 4];
      }
    }
    __syncthreads();
    if (wv < 4) __builtin_amdgcn_s_setprio(1);   // cells win SIMD arbitration

    int cons0L = 0;
    f4 tr0 = {0.f, 0.f, 0.f, 0.f}, tr1 = {0.f, 0.f, 0.f, 0.f};
    for (int t = 0; t <= T; ++t) {
      if (wv < 4) {
        if (t < T) {
          const float* base = &h0r[(t - 1) & 3][16 * k];
          f2 P0 = {0.f,0.f}, P1 = {0.f,0.f}, P2 = {0.f,0.f}, P3 = {0.f,0.f};
          #pragma unroll
          for (int c = 0; c < 4; ++c) {
            f4 v = *(const f4*)(base + 4 * ((c + k) & 3));
            P0 += wreg[2*c] * v.lo;      P0 += wreg[2*c+1] * v.hi;
            P1 += wreg[8+2*c] * v.lo;    P1 += wreg[8+2*c+1] * v.hi;
            P2 += wreg[16+2*c] * v.lo;   P2 += wreg[16+2*c+1] * v.hi;
            P3 += wreg[24+2*c] * v.lo;   P3 += wreg[24+2*c+1] * v.hi;
          }
          float p0 = P0.x + P0.y, p1 = P1.x + P1.y;
          float p2 = P2.x + P2.y, p3 = P3.x + P3.y;
          float g = ((p0 + qp<0x39>(p3)) + (qp<0x4E>(p2) + qp<0x93>(p1))) + b_ + xc;
          float e = __expf(-g * am);
          float s = __fdividef(1.0f, 1.0f + e);
          float a = fmaf(s, am, ab);
          float A1 = qp<0xB1>(a), A2 = qp<0x4E>(a), A3 = qp<0x1B>(a);
          if (isk0) {
            cS = A1 * cS + a * A2;
            float e2 = __expf(-2.0f * cS);
            hS = A3 * (__fdividef(2.0f, 1.0f + e2) - 1.0f);
            h0r[t & 3][u] = hS;
          }
        }
        if (t < T - 1) {
          const f4* trow = (const f4*)&tbuf[(t >> 5) & 1][(t & 31) * NF];
          f4 r0 = trow[0], r1 = trow[1];
          f2 s2 = wreg[32] * r0.lo; s2 += wreg[33] * r0.hi;
          s2 += wreg[34] * r1.lo;   s2 += wreg[35] * r1.hi;
          xc = xd + s2.x + s2.y;
        } else xc = 0.f;
      } else {
        // -------- pub0: release, backpressure, ring store, tbuf --------
        if ((t & 3) == 0 && t >= 8) {
          WAIT_VM(4);   // FIFO: ring entries <= t-7 durable; 4 newest in flight
          if (l == 0) st_cohi(flag0p, t - 6);
        }
        if ((t & 63) == 0 && t > RD - 64) {
          while (t - cons0L > RD - 64) {
            cons0L = ld_cohi(cons0p);
            WAIT_VM(0);
          }
        }
        if (t >= 1) {
          float hv = h0r[(t - 1) & 3][l];
          st_cohf(&ring0[((t - 1) & RMASK) * 64 + l], hv);
        }
        const int ph = t & 31;
        const int cl = (t >> 5) + 1;
        if (l < 32 && cl * 32 < T) {
          if (ph == 8) {
            tr0 = *(const f4*)&target[cl * 256 + l * 8];
            tr1 = *(const f4*)&target[cl * 256 + l * 8 + 4];
          } else if (ph == 26) {
            *(f4*)&tbuf[cl & 1][l * 8]     = tr0;
            *(f4*)&tbuf[cl & 1][l * 8 + 4] = tr1;
          }
        }
      }
      wg_barrier();
    }
    if (wv == 4) {
      WAIT_VM(0);
      if (l == 0) st_cohi(flag0p, T);
    }
    if (wv < 4 && isk0) {
      outp[T * NF + u]       = hS;   // h_final layer 0
      outp[T * NF + 128 + u] = cS;   // c_final layer 0
    }
  } else if (blockIdx.x == 1) {
    // ================= BLOCK 1 : layer 1 =================
    f2 wreg[64];
    float b_ = 0.f, cS = 0.f, hS = 0.f;
    if (wv < 4) {
      const float* Wsrc = (k < 2) ? Wih1 : Whh1;
      const int co = 32 * (k & 1);
      #pragma unroll
      for (int j = 0; j < 4; ++j) {
        const int row = 64 * ((k + j) & 3) + u;
        const float* rp = Wsrc + row * 64 + co;
        #pragma unroll
        for (int c = 0; c < 8; ++c) {
          f4 v = *(const f4*)(rp + 4 * ((c + 2 * k) & 7));
          wreg[16 * j + 2 * c]     = v.lo;
          wreg[16 * j + 2 * c + 1] = v.hi;
        }
      }
      b_ = bih1[r] + bhh1[r];
      if (isk0) cS = c0in[64 + u];
      if (wv == 0) h1r[3][l] = h0in[64 + l];
    }
    // dma state
    int flagL = 0, fillW = 0, nPend = 0, F_pend = 0, cons1L = 0;
    float pb0 = 0.f, pb1 = 0.f, pb2 = 0.f, pb3 = 0.f;
    if (wv == 4) {
      const int pre = (T < 4) ? T : 4;
      while (flagL < pre) {
        flagL = ld_cohi(flag0p);
        WAIT_VM(0);
      }
      for (int s = 0; s < pre; ++s) {
        float v = ld_cohf(&ring0[(s & RMASK) * 64 + l]);
        WAIT_VM(0);
        h0loc[s & 15][l] = v;
      }
      fillW = pre;
      F_pend = flagL;
    }
    __syncthreads();
    if (wv < 4) __builtin_amdgcn_s_setprio(1);   // cells win SIMD arbitration

    for (int p = 0; p <= T; ++p) {
      if (wv < 4) {
        if (p < T) {
          const float* base = (k < 2) ? &h0loc[p & 15][32 * (k & 1)]
                                      : &h1r[(p - 1) & 3][32 * (k & 1)];
          f2 P0 = {0.f,0.f}, P1 = {0.f,0.f}, P2 = {0.f,0.f}, P3 = {0.f,0.f};
          #pragma unroll
          for (int c = 0; c < 8; ++c) {
            f4 v = *(const f4*)(base + 4 * ((c + 2 * k) & 7));
            P0 += wreg[2*c] * v.lo;      P0 += wreg[2*c+1] * v.hi;
            P1 += wreg[16+2*c] * v.lo;   P1 += wreg[16+2*c+1] * v.hi;
            P2 += wreg[32+2*c] * v.lo;   P2 += wreg[32+2*c+1] * v.hi;
            P3 += wreg[48+2*c] * v.lo;   P3 += wreg[48+2*c+1] * v.hi;
          }
          float p0 = P0.x + P0.y, p1 = P1.x + P1.y;
          float p2 = P2.x + P2.y, p3 = P3.x + P3.y;
          float g = ((p0 + qp<0x39>(p3)) + (qp<0x4E>(p2) + qp<0x93>(p1))) + b_;
          float e = __expf(-g * am);
          float s = __fdividef(1.0f, 1.0f + e);
          float a = fmaf(s, am, ab);
          float A1 = qp<0xB1>(a), A2 = qp<0x4E>(a), A3 = qp<0x1B>(a);
          if (isk0) {
            cS = A1 * cS + a * A2;
            float e2 = __expf(-2.0f * cS);
            hS = A3 * (__fdividef(2.0f, 1.0f + e2) - 1.0f);
            h1r[p & 3][u] = hS;
          }
        }
      } else if (wv == 4) {
        // -------- dma: keep h0loc >= p+2 filled, prefetch to p+10 --------
        WAIT_VM(1);   // pending loads (issued p-1) done; newest h1 store may fly
        if (nPend > 0) h0loc[(fillW + 0) & 15][l] = pb0;
        if (nPend > 1) h0loc[(fillW + 1) & 15][l] = pb1;
        if (nPend > 2) h0loc[(fillW + 2) & 15][l] = pb2;
        if (nPend > 3) h0loc[(fillW + 3) & 15][l] = pb3;
        fillW += nPend;
        nPend = 0;
        if ((p & 3) == 1) flagL = F_pend;   // adopt poll issued at p-1
        {  // emergency (startup/starved only)
          int need = p + 2; if (need > T) need = T;
          while (fillW < need) {
            while (flagL < fillW + 1) {
              flagL = ld_cohi(flag0p);
              WAIT_VM(0);
            }
            float v = ld_cohf(&ring0[(fillW & RMASK) * 64 + l]);
            WAIT_VM(0);
            h0loc[fillW & 15][l] = v;
            ++fillW;
          }
        }
        if ((p & 3) == 0 && p >= 8 && l == 0)
          st_cohi(flag1p, p - 6);   // outstanding <=1 (from p-1) => safe
        if ((p & 63) == 0 && p > RD - 64) {
          while (p - cons1L > RD - 64) {
            cons1L = ld_cohi(cons1p);
            WAIT_VM(0);
          }
        }
        if ((p & 3) == 0) F_pend = ld_cohi(flag0p);   // adopt at p+1
        {
          int want = flagL;
          if (want > p + 10) want = p + 10;
          if (want > T) want = T;
          int n = want - fillW;
          if (n < 0) n = 0;
          if (n > 4) n = 4;
          if (n > 0) pb0 = ld_cohf(&ring0[((fillW + 0) & RMASK) * 64 + l]);
          if (n > 1) pb1 = ld_cohf(&ring0[((fillW + 1) & RMASK) * 64 + l]);
          if (n > 2) pb2 = ld_cohf(&ring0[((fillW + 2) & RMASK) * 64 + l]);
          if (n > 3) pb3 = ld_cohf(&ring0[((fillW + 3) & RMASK) * 64 + l]);
          nPend = n;
        }
        if (p >= 1) {
          float hv = h1r[(p - 1) & 3][l];
          st_cohf(&ring1[((p - 1) & RMASK) * 64 + l], hv);
        }
        if ((p & 63) == 32 && l == 0) st_cohi(cons0p, fillW);
      }
      wg_barrier();
    }
    if (wv == 4) {
      WAIT_VM(0);
      if (l == 0) st_cohi(flag1p, T);
    }
    if (wv < 4 && isk0) {
      outp[T * NF + 64 + u]  = hS;   // h_final layer 1
      outp[T * NF + 192 + u] = cS;   // c_final layer 1
    }
  } else {
    // ================= BLOCK 2 : head (self-paced, 1 wave) =================
    if (wv != 0) return;
    f2 wH[16], wO[4];
    float bhA = 0.f, bhB = 0.f, bo_ = 0.f;
    #pragma unroll
    for (int i = 0; i < 2; ++i) {
      const float* rp = Whid + (2 * q + i) * 64 + 16 * k;
      #pragma unroll
      for (int c = 0; c < 4; ++c) {
        f4 v = *(const f4*)(rp + 4 * ((c + k) & 3));
        wH[8 * i + 2 * c]     = v.lo;
        wH[8 * i + 2 * c + 1] = v.hi;
      }
    }
    bhA = bhidp[2 * q];
    bhB = bhidp[2 * q + 1];
    if (q < 8) {
      const float* rp = Woutp + q * 32 + 8 * k;
      #pragma unroll
      for (int c = 0; c < 2; ++c) {
        f4 v = *(const f4*)(rp + 4 * ((c + k) & 1));
        wO[2 * c]     = v.lo;
        wO[2 * c + 1] = v.hi;
      }
      bo_ = boutp[q];
    }
    int f1L = 0;
    for (int s0 = 0; s0 < T; s0 += 8) {
      const int B = (T - s0 < 8) ? (T - s0) : 8;
      while (f1L < s0 + B) {
        f1L = ld_cohi(flag1p);
        WAIT_VM(0);
      }
      float rb[8];
      #pragma unroll
      for (int i = 0; i < 8; ++i)
        if (i < B) rb[i] = ld_cohf(&ring1[((s0 + i) & RMASK) * 64 + l]);
      WAIT_VM(0);
      #pragma unroll
      for (int i = 0; i < 8; ++i)
        if (i < B) h1loc[(s0 + i) & 7][l] = rb[i];
      #pragma unroll
      for (int i = 0; i < 8; ++i) {
        if (i < B) {
          const int s = s0 + i;
          // hid (verbatim R7)
          const float* hp = &h1loc[s & 7][16 * k];
          f2 pa = {0.f,0.f}, pb = {0.f,0.f};
          #pragma unroll
          for (int c = 0; c < 4; ++c) {
            f4 v = *(const f4*)(hp + 4 * ((c + k) & 3));
            pa += wH[2*c] * v.lo;     pa += wH[2*c+1] * v.hi;
            pb += wH[8+2*c] * v.lo;   pb += wH[8+2*c+1] * v.hi;
          }
          float sa = pa.x + pa.y; sa += qp<0xB1>(sa); sa += qp<0x4E>(sa);
          float sb = pb.x + pb.y; sb += qp<0xB1>(sb); sb += qp<0x4E>(sb);
          if (isk0) *(f2*)&hidS[s & 3][2 * q] = (f2){sa + bhA, sb + bhB};
          // out (verbatim R7)
          if (q < 8) {
            const float* hq = &hidS[s & 3][8 * k];
            f2 po = {0.f,0.f};
            #pragma unroll
            for (int c = 0; c < 2; ++c) {
              f4 v = *(const f4*)(hq + 4 * ((c + k) & 1));
              po += wO[2*c] * v.lo; po += wO[2*c+1] * v.hi;
            }
            float so = po.x + po.y; so += qp<0xB1>(so); so += qp<0x4E>(so);
            if (isk0) outp[s * NF + q] = rintf(so + bo_);
          }
        }
      }
      if ((s0 & 63) == 0 && s0 > 0 && l == 0) st_cohi(cons1p, s0);
    }
  }
}

extern "C" void kernel_launch(void* const* d_in, const int* in_sizes, int n_in,
                              void* d_out, int out_size, void* d_ws, size_t ws_size,
                              hipStream_t stream) {
  const float* h0in   = (const float*)d_in[1];
  const float* c0in   = (const float*)d_in[2];
  const float* diffp  = (const float*)d_in[3];
  const float* target = (const float*)d_in[4];
  const float* Wih0   = (const float*)d_in[5];
  const float* Whh0   = (const float*)d_in[6];
  const float* bih0   = (const float*)d_in[7];
  const float* bhh0   = (const float*)d_in[8];
  const float* Wih1   = (const float*)d_in[9];
  const float* Whh1   = (const float*)d_in[10];
  const float* bih1   = (const float*)d_in[11];
  const float* bhh1   = (const float*)d_in[12];
  const float* Whid   = (const float*)d_in[13];
  const float* bhidp  = (const float*)d_in[14];
  const float* Woutp  = (const float*)d_in[15];
  const float* boutp  = (const float*)d_in[16];
  float* outp = (float*)d_out;
  const int T = in_sizes[4] / NF;

  hipMemsetAsync(d_ws, 0, 256, stream);   // zero flags (graph-capturable)
  decoder_p14<<<dim3(3), dim3(320), 0, stream>>>(
      h0in, c0in, diffp, target,
      Wih0, Whh0, bih0, bhh0,
      Wih1, Whh1, bih1, bhh1,
      Whid, bhidp, Woutp, boutp,
      outp, (float*)d_ws, T);
}